// Round 3
// baseline (260.501 us; speedup 1.0000x reference)
//
#include <hip/hip_runtime.h>

// ---------------------------------------------------------------------------
// EdgeFeatureNet: B=1, N=512, NODE_DIM=256, HID=128, EDGE_DIM=128, bins=22
// Inputs: float32. Output: float32 (reference dtype; harness reads f32).
//
// Factorization of layer 1 (feats @ W1 + b1):
//   h1_pre[i,j] = A[i] + Bv[j] + R[i-j+511] + W1row[384+binD] + W1row[406+binS]
//   A[i]  = n2e[i]@W1[0:128]   + b1 + flow[i]*W1[428]
//   Bv[j] = n2e[j]@W1[128:256]      + flow[j]*W1[429]
//   R[d]  = (embed(d)@W_rp + b_rp) @ W1[256:384]
// Then h2 = relu(h1@W2+b2), h3 = h2@W3+b3, LayerNorm, * edge_mask.
// Layers 2/3 via mfma_f32_16x16x32_bf16 (bf16 activations/weights, f32 acc).
// ---------------------------------------------------------------------------

using bf16x8 = __attribute__((ext_vector_type(8))) short;
using f32x4  = __attribute__((ext_vector_type(4))) float;

__device__ __forceinline__ unsigned short f2bf(float f) {
    unsigned int u;
    __builtin_memcpy(&u, &f, 4);
    unsigned int r = (u + 0x7fffu + ((u >> 16) & 1u)) >> 16;  // RNE
    return (unsigned short)r;
}

// ---------------------------------------------------------------------------
// Precompute per-node A[i], Bv[i] (includes b1 / flow folds). grid=512, blk=128
// ---------------------------------------------------------------------------
__global__ void pre_node(const float* __restrict__ nf,
                         const float* __restrict__ Wn2e,
                         const float* __restrict__ bn2e,
                         const float* __restrict__ W1,
                         const float* __restrict__ b1,
                         const float* __restrict__ flow,
                         float* __restrict__ A, float* __restrict__ Bv)
{
    __shared__ float nfs[256];
    __shared__ float n2s[128];
    const int i = blockIdx.x, f = threadIdx.x;
    nfs[f]       = nf[i * 256 + f];
    nfs[f + 128] = nf[i * 256 + 128 + f];
    __syncthreads();
    float acc = bn2e[f];
    for (int k = 0; k < 256; k++) acc += nfs[k] * Wn2e[k * 128 + f];
    n2s[f] = acc;
    __syncthreads();
    const float fl = flow[i];
    float aA = b1[f] + fl * W1[428 * 128 + f];
    float aB =         fl * W1[429 * 128 + f];
    for (int k = 0; k < 128; k++) {
        const float s = n2s[k];
        aA += s * W1[k * 128 + f];
        aB += s * W1[(128 + k) * 128 + f];
    }
    A[i * 128 + f]  = aA;
    Bv[i * 128 + f] = aB;
}

// ---------------------------------------------------------------------------
// Precompute R[d] for d = i-j in [-511,511] (index d+511). grid=1023, blk=128
// ---------------------------------------------------------------------------
__global__ void pre_rel(const float* __restrict__ Wrp,
                        const float* __restrict__ brp,
                        const float* __restrict__ W1,
                        float* __restrict__ Rm)
{
    __shared__ float emb[128];
    __shared__ float rp[128];
    const int dix = blockIdx.x;
    const float d = (float)(dix - 511);
    const int m = threadIdx.x;
    const int K = m & 63;
    const float denom = powf(2056.0f, (float)K * (1.0f / 64.0f));
    const float ang = d * 3.14159265358979323846f / denom;
    emb[m] = (m < 64) ? sinf(ang) : cosf(ang);
    __syncthreads();
    float acc = brp[m];
    for (int k = 0; k < 128; k++) acc += emb[k] * Wrp[k * 128 + m];
    rp[m] = acc;
    __syncthreads();
    float acc2 = 0.0f;
    for (int k = 0; k < 128; k++) acc2 += rp[k] * W1[(256 + k) * 128 + m];
    Rm[dix * 128 + m] = acc2;
}

// ---------------------------------------------------------------------------
// Main fused kernel: grid=1024 (i = bid>>1, j0 = (bid&1)*256), block=512 (8 waves)
// Each wave owns 32 pairs (rows of hbuf are wave-private). LDS ~137 KB.
// ---------------------------------------------------------------------------
__global__ __launch_bounds__(512, 2) void edge_main(
    const float* __restrict__ trans,
    const float* __restrict__ sctrans,
    const float* __restrict__ emask,
    const float* __restrict__ W1,
    const float* __restrict__ W2,
    const float* __restrict__ b2,
    const float* __restrict__ W3,
    const float* __restrict__ b3,
    const float* __restrict__ lng,
    const float* __restrict__ lnb,
    const float* __restrict__ A,
    const float* __restrict__ Bv,
    const float* __restrict__ Rm,
    float* __restrict__ out)
{
    // W2L/W3L layout: [kg=k>>3][n][j=k&7] so a B-fragment read is ds_read_b128
    __shared__ __align__(16) short W2L[16 * 128 * 8];
    __shared__ __align__(16) short W3L[16 * 128 * 8];
    __shared__ __align__(16) short hbuf[256 * 136];  // pitch 136 (+8 pad)
    __shared__ __align__(16) float As[128];
    __shared__ int binsD[256];
    __shared__ int binsS[256];

    const int tid = threadIdx.x;
    const int i  = blockIdx.x >> 1;
    const int j0 = (blockIdx.x & 1) << 8;

    // ---- stage W2/W3 (f32 -> bf16) into fragment-friendly LDS layout ----
    for (int idx = tid; idx < 16384; idx += 512) {
        const int k = idx >> 7, n = idx & 127;
        const int dst = ((k >> 3) * 128 + n) * 8 + (k & 7);
        W2L[dst] = (short)f2bf(W2[idx]);
        W3L[dst] = (short)f2bf(W3[idx]);
    }
    if (tid < 128) As[tid] = A[i * 128 + tid];

    // ---- per-pair distogram bins (threads 0..255: trans, 256..511: sc_trans)
    // np semantics: edges from float64 linspace, d is f32 (un-contracted), cmp in f64
    {
        const int p = tid & 255;
        const float* P = (tid < 256) ? trans : sctrans;
        const int j = j0 + p;
        const float dx = __fsub_rn(P[i * 3 + 0], P[j * 3 + 0]);
        const float dy = __fsub_rn(P[i * 3 + 1], P[j * 3 + 1]);
        const float dz = __fsub_rn(P[i * 3 + 2], P[j * 3 + 2]);
        const float d2 = __fadd_rn(__fadd_rn(__fmul_rn(dx, dx), __fmul_rn(dy, dy)),
                                   __fmul_rn(dz, dz));
        const double dd = (double)sqrtf(d2);
        const double step = (20.0 - 0.001) / 21.0;
        int bin = -1;
        for (int b = 0; b < 22; b++) {
            const double lo = (b == 21) ? 20.0 : __dadd_rn(0.001, __dmul_rn((double)b, step));
            const double up = (b == 20) ? 20.0 :
                              ((b == 21) ? 1e8 : __dadd_rn(0.001, __dmul_rn((double)(b + 1), step)));
            if (dd > lo && dd < up) bin = b;
        }
        if (tid < 256) binsD[p] = bin; else binsS[p] = bin;
    }
    __syncthreads();

    const int w = tid >> 6;       // wave id: owns pairs [32w, 32w+32)
    const int l = tid & 63;
    const int q = l >> 4;         // quad within wave
    const int ln16 = l & 15;

    // ---- h1 assembly: pairs [32w,32w+32) x 128 feats, float4 per lane-iter
    for (int it = 0; it < 16; it++) {
        const int flat = it * 64 + l;          // 0..1023 = 32 pairs * 32 f4
        const int p = 32 * w + (flat >> 5);
        const int f = (flat & 31) << 2;
        const int j = j0 + p;
        const int didx = i - j + 511;
        const f32x4 bv = *(const f32x4*)&Bv[j * 128 + f];
        const f32x4 r  = *(const f32x4*)&Rm[didx * 128 + f];
        const f32x4 a  = *(const f32x4*)&As[f];
        const int bD = binsD[p], bS = binsS[p];
        const float sD = bD >= 0 ? 1.0f : 0.0f;
        const float sS = bS >= 0 ? 1.0f : 0.0f;
        const int rD = 384 + (bD >= 0 ? bD : 0);
        const int rS = 406 + (bS >= 0 ? bS : 0);
        const f32x4 wd  = *(const f32x4*)&W1[rD * 128 + f];
        const f32x4 wsv = *(const f32x4*)&W1[rS * 128 + f];
        float h0 = a.x + bv.x + r.x + sD * wd.x + sS * wsv.x;
        float h1 = a.y + bv.y + r.y + sD * wd.y + sS * wsv.y;
        float h2 = a.z + bv.z + r.z + sD * wd.z + sS * wsv.z;
        float h3 = a.w + bv.w + r.w + sD * wd.w + sS * wsv.w;
        h0 = fmaxf(h0, 0.0f); h1 = fmaxf(h1, 0.0f);
        h2 = fmaxf(h2, 0.0f); h3 = fmaxf(h3, 0.0f);
        uint2 pk;
        pk.x = (unsigned int)f2bf(h0) | ((unsigned int)f2bf(h1) << 16);
        pk.y = (unsigned int)f2bf(h2) | ((unsigned int)f2bf(h3) << 16);
        *(uint2*)&hbuf[p * 136 + f] = pk;
    }
    __syncthreads();

    // ---- layer 2: h2 = relu(h1 @ W2 + b2), 2 M-tiles of 16 pairs per wave
    bf16x8 af[2][4];
    for (int mt = 0; mt < 2; mt++)
        for (int kb = 0; kb < 4; kb++)
            af[mt][kb] = *(const bf16x8*)&hbuf[(32 * w + mt * 16 + ln16) * 136 + q * 8 + kb * 32];

    const f32x4 vzero = {0.0f, 0.0f, 0.0f, 0.0f};
    f32x4 acc[2][8];
    for (int mt = 0; mt < 2; mt++)
        for (int nb = 0; nb < 8; nb++) acc[mt][nb] = vzero;

    for (int nb = 0; nb < 8; nb++) {
        for (int kb = 0; kb < 4; kb++) {
            const bf16x8 bfrg = *(const bf16x8*)&W2L[((kb * 4 + q) * 128 + nb * 16 + ln16) * 8];
            acc[0][nb] = __builtin_amdgcn_mfma_f32_16x16x32_bf16(af[0][kb], bfrg, acc[0][nb], 0, 0, 0);
            acc[1][nb] = __builtin_amdgcn_mfma_f32_16x16x32_bf16(af[1][kb], bfrg, acc[1][nb], 0, 0, 0);
        }
    }
    __syncthreads();

    // write h2 back (C-layout -> row-major LDS), relu + bias
    float b2v[8];
    for (int nb = 0; nb < 8; nb++) b2v[nb] = b2[nb * 16 + ln16];
    for (int nb = 0; nb < 8; nb++)
        for (int mt = 0; mt < 2; mt++)
            for (int rg = 0; rg < 4; rg++) {
                float v = acc[mt][nb][rg] + b2v[nb];
                v = fmaxf(v, 0.0f);
                const int p = 32 * w + mt * 16 + q * 4 + rg;
                hbuf[p * 136 + nb * 16 + ln16] = (short)f2bf(v);
            }
    __syncthreads();

    // ---- layer 3: h3 = h2 @ W3 + b3
    for (int mt = 0; mt < 2; mt++)
        for (int kb = 0; kb < 4; kb++)
            af[mt][kb] = *(const bf16x8*)&hbuf[(32 * w + mt * 16 + ln16) * 136 + q * 8 + kb * 32];
    for (int mt = 0; mt < 2; mt++)
        for (int nb = 0; nb < 8; nb++) acc[mt][nb] = vzero;
    for (int nb = 0; nb < 8; nb++) {
        for (int kb = 0; kb < 4; kb++) {
            const bf16x8 bfrg = *(const bf16x8*)&W3L[((kb * 4 + q) * 128 + nb * 16 + ln16) * 8];
            acc[0][nb] = __builtin_amdgcn_mfma_f32_16x16x32_bf16(af[0][kb], bfrg, acc[0][nb], 0, 0, 0);
            acc[1][nb] = __builtin_amdgcn_mfma_f32_16x16x32_bf16(af[1][kb], bfrg, acc[1][nb], 0, 0, 0);
        }
    }

    // ---- epilogue: +b3, LayerNorm over 128 (quad butterfly), *mask, f32 store
    float b3v[8], gv[8], bbv[8];
    for (int nb = 0; nb < 8; nb++) {
        const int n = nb * 16 + ln16;
        b3v[nb] = b3[n];
        gv[nb]  = lng[n];
        bbv[nb] = lnb[n];
    }
    for (int mt = 0; mt < 2; mt++) {
        for (int rg = 0; rg < 4; rg++) {
            float v[8];
            float s = 0.0f;
            for (int nb = 0; nb < 8; nb++) { v[nb] = acc[mt][nb][rg] + b3v[nb]; s += v[nb]; }
            for (int m = 1; m < 16; m <<= 1) s += __shfl_xor(s, m, 64);
            const float mu = s * (1.0f / 128.0f);
            float ss = 0.0f;
            for (int nb = 0; nb < 8; nb++) { const float dv = v[nb] - mu; ss += dv * dv; }
            for (int m = 1; m < 16; m <<= 1) ss += __shfl_xor(ss, m, 64);
            const float rstd = rsqrtf(ss * (1.0f / 128.0f) + 1e-5f);
            const int p = 32 * w + mt * 16 + q * 4 + rg;
            const int j = j0 + p;
            const float msk = emask[i * 512 + j];
            const int obase = (i * 512 + j) * 128;
            for (int nb = 0; nb < 8; nb++) {
                const float o = ((v[nb] - mu) * rstd * gv[nb] + bbv[nb]) * msk;
                out[obase + nb * 16 + ln16] = o;
            }
        }
    }
}

// ---------------------------------------------------------------------------
extern "C" void kernel_launch(void* const* d_in, const int* in_sizes, int n_in,
                              void* d_out, int out_size, void* d_ws, size_t ws_size,
                              hipStream_t stream)
{
    const float* nf    = (const float*)d_in[0];
    const float* trans = (const float*)d_in[1];
    const float* sctr  = (const float*)d_in[2];
    const float* emask = (const float*)d_in[3];
    const float* flow  = (const float*)d_in[4];
    const float* Wn2e  = (const float*)d_in[5];
    const float* bn2e  = (const float*)d_in[6];
    const float* Wrp   = (const float*)d_in[7];
    const float* brp   = (const float*)d_in[8];
    const float* W1    = (const float*)d_in[9];
    const float* b1    = (const float*)d_in[10];
    const float* W2    = (const float*)d_in[11];
    const float* b2    = (const float*)d_in[12];
    const float* W3    = (const float*)d_in[13];
    const float* b3    = (const float*)d_in[14];
    const float* lng   = (const float*)d_in[15];
    const float* lnb   = (const float*)d_in[16];

    float* ws = (float*)d_ws;                  // needs 262016 floats ~ 1.05 MB
    float* A  = ws;                            // [512*128]
    float* Bv = ws + 512 * 128;                // [512*128]
    float* Rm = ws + 2 * 512 * 128;            // [1023*128]
    float* out = (float*)d_out;

    pre_node<<<512, 128, 0, stream>>>(nf, Wn2e, bn2e, W1, b1, flow, A, Bv);
    pre_rel<<<1023, 128, 0, stream>>>(Wrp, brp, W1, Rm);
    edge_main<<<1024, 512, 0, stream>>>(trans, sctr, emask, W1, W2, b2, W3, b3,
                                        lng, lnb, A, Bv, Rm, out);
}